// Round 12
// baseline (1785.435 us; speedup 1.0000x reference)
//
#include <hip/hip_runtime.h>
#include <hip/hip_bf16.h>

#define NB 8
#define NC 256
#define NH_ 8
#define NLAYERS_ 6
#define FFN_ 1024
#define Q_ 5440
#define DH_ 32
#define M_ (NB*Q_)        // 43520
#define MC2 (M_/2)        // 21760  (FFN chunk rows)

typedef __attribute__((ext_vector_type(8))) short bf16x8;
typedef __attribute__((ext_vector_type(4))) short bf16x4;
typedef __attribute__((ext_vector_type(4))) float f32x4;
typedef __attribute__((ext_vector_type(4))) int i32x4;
typedef __attribute__((ext_vector_type(4))) unsigned int u32x4;
typedef unsigned int u32;

__device__ __forceinline__ unsigned short f2bf(float f) {
  unsigned int u = __float_as_uint(f);
  u += 0x7fffu + ((u >> 16) & 1u);
  return (unsigned short)(u >> 16);
}
__device__ __forceinline__ float bf2f(unsigned short s) {
  return __uint_as_float(((unsigned int)s) << 16);
}
__device__ __forceinline__ void gl16(const unsigned short* g, unsigned short* l) {
  __builtin_amdgcn_global_load_lds((const __attribute__((address_space(1))) u32*)(g),
                                   (__attribute__((address_space(3))) u32*)(l), 16, 0, 0);
}
__device__ __forceinline__ void unp8(bf16x8 v, f32x4& lo, f32x4& hi) {
  u32x4 g = __builtin_bit_cast(u32x4, v);
  lo[0] = __uint_as_float(g[0] << 16); lo[1] = __uint_as_float(g[0] & 0xffff0000u);
  lo[2] = __uint_as_float(g[1] << 16); lo[3] = __uint_as_float(g[1] & 0xffff0000u);
  hi[0] = __uint_as_float(g[2] << 16); hi[1] = __uint_as_float(g[2] & 0xffff0000u);
  hi[2] = __uint_as_float(g[3] << 16); hi[3] = __uint_as_float(g[3] & 0xffff0000u);
}
__device__ __forceinline__ bf16x8 pck8(f32x4 lo, f32x4 hi) {
  bf16x8 o;
  o[0] = (short)f2bf(lo[0]); o[1] = (short)f2bf(lo[1]);
  o[2] = (short)f2bf(lo[2]); o[3] = (short)f2bf(lo[3]);
  o[4] = (short)f2bf(hi[0]); o[5] = (short)f2bf(hi[1]);
  o[6] = (short)f2bf(hi[2]); o[7] = (short)f2bf(hi[3]);
  return o;
}

// ---------------- prep kernels ----------------
__global__ void transpose_w2_k(const float* __restrict__ W, unsigned short* __restrict__ Wt,
                               int L, int Kd, int Nd, int NdTot, int nOff) {
  size_t total = (size_t)L * Nd * Kd;
  for (size_t i = (size_t)blockIdx.x * blockDim.x + threadIdx.x; i < total;
       i += (size_t)gridDim.x * blockDim.x) {
    int k = (int)(i % Kd);
    size_t r = i / Kd;
    int n = (int)(r % Nd);
    int l = (int)(r / Nd);
    Wt[((size_t)l * NdTot + nOff + n) * Kd + k] = f2bf(W[((size_t)l * Kd + k) * Nd + n]);
  }
}

__global__ void bias_cat_k(const float* __restrict__ bs, const float* __restrict__ ba,
                           float* __restrict__ bsa) {
  int i = blockIdx.x * blockDim.x + threadIdx.x;
  if (i >= NLAYERS_ * 384) return;
  int l = i / 384, n = i % 384;
  bsa[i] = (n < 256) ? bs[l * 256 + n] : ba[l * 128 + (n - 256)];
}

// layer-0: xb=bf16(src), pe=bf16(pos+lvl), qb=bf16(src+pos+lvl)
__global__ __launch_bounds__(256)
void pre_k(const float* __restrict__ src, const float* __restrict__ pf,
           const float* __restrict__ le, unsigned short* __restrict__ xb,
           unsigned short* __restrict__ pe, unsigned short* __restrict__ qb) {
  int row = blockIdx.x * 4 + (threadIdx.x >> 6);
  int lane = threadIdx.x & 63;
  size_t base = (size_t)row * NC + lane * 4;
  int q = row % Q_;
  int lvl = q < 4096 ? 0 : (q < 5120 ? 1 : (q < 5376 ? 2 : 3));
  f32x4 xv = *(const f32x4*)(src + base);
  f32x4 pv = *(const f32x4*)(pf + base) + *(const f32x4*)(le + lvl * NC + lane * 4);
  f32x4 qv = xv + pv;
  bf16x4 xo, po, qo;
#pragma unroll
  for (int j = 0; j < 4; ++j) {
    xo[j] = (short)f2bf(xv[j]); po[j] = (short)f2bf(pv[j]); qo[j] = (short)f2bf(qv[j]);
  }
  *(bf16x4*)(xb + base) = xo;
  *(bf16x4*)(pe + base) = po;
  *(bf16x4*)(qb + base) = qo;
}

__device__ __forceinline__ int swz(int r, int sl) { return sl ^ (r & 3) ^ ((r >> 2) & 3); }

// ---------------- 256-thread GEMM, tile 128x128 (value + sa only) ---------
#define ES 136
#define SHN 24576  // shorts: 3 bufs x 8192

__device__ __forceinline__ void gemm_body(const unsigned short* X, const unsigned short* Wt,
                                          const float* bias, unsigned short* Y,
                                          int Kdim, int Ndim, int n0, int m0,
                                          unsigned short* SH) {
  const int t = threadIdx.x;
  const int wave = t >> 6, lane = t & 63;
  const int wr = wave >> 1, wc = wave & 1;
  const int lr = lane & 15, lk = lane >> 4;
  const int r0 = t >> 2, sl0 = t & 3;
  const int r1 = (256 + t) >> 2;
  const int gs0 = swz(r0, sl0);
  const int gs1 = swz(r1, sl0);
  const unsigned short* xp0 = X + (size_t)(m0 + r0) * Kdim + gs0 * 8;
  const unsigned short* wp0 = Wt + (size_t)(n0 + r0) * Kdim + gs0 * 8;
  const unsigned short* xp1 = X + (size_t)(m0 + r1) * Kdim + gs1 * 8;
  const unsigned short* wp1 = Wt + (size_t)(n0 + r1) * Kdim + gs1 * 8;

  f32x4 acc[4][4];
#pragma unroll
  for (int i = 0; i < 4; ++i)
#pragma unroll
    for (int j = 0; j < 4; ++j)
#pragma unroll
      for (int e = 0; e < 4; ++e) acc[i][j][e] = 0.f;

  auto stage = [&](int buf, int kt) {
    unsigned short* base = SH + buf * 8192;
    gl16(xp0 + kt, base + t * 8);
    gl16(wp0 + kt, base + 4096 + t * 8);
    gl16(xp1 + kt, base + (256 + t) * 8);
    gl16(wp1 + kt, base + 4096 + (256 + t) * 8);
  };

  const int nt = Kdim >> 5;
  stage(0, 0);
  stage(1, 32);
  asm volatile("s_waitcnt vmcnt(4)" ::: "memory");
  __builtin_amdgcn_s_barrier();

  int buf = 0;
  for (int ti = 0; ti < nt; ++ti) {
    if (ti + 2 < nt) stage(buf == 0 ? 2 : buf - 1, (ti + 2) << 5);
    const unsigned short* Ab = SH + buf * 8192;
    const unsigned short* Bb = Ab + 4096;
    bf16x8 ar[4], br[4];
#pragma unroll
    for (int fi = 0; fi < 4; ++fi) {
      int r = wr * 64 + fi * 16 + lr;
      ar[fi] = *(const bf16x8*)&Ab[r * 32 + swz(r, lk) * 8];
    }
#pragma unroll
    for (int fj = 0; fj < 4; ++fj) {
      int r = wc * 64 + fj * 16 + lr;
      br[fj] = *(const bf16x8*)&Bb[r * 32 + swz(r, lk) * 8];
    }
#pragma unroll
    for (int fi = 0; fi < 4; ++fi)
#pragma unroll
      for (int fj = 0; fj < 4; ++fj)
        acc[fi][fj] = __builtin_amdgcn_mfma_f32_16x16x32_bf16(ar[fi], br[fj], acc[fi][fj], 0, 0, 0);
    if (ti + 2 < nt)
      asm volatile("s_waitcnt vmcnt(4)" ::: "memory");
    else
      asm volatile("s_waitcnt vmcnt(0)" ::: "memory");
    __builtin_amdgcn_s_barrier();
    buf = (buf == 2) ? 0 : buf + 1;
  }

#pragma unroll
  for (int fi = 0; fi < 4; ++fi)
#pragma unroll
    for (int fj = 0; fj < 4; ++fj) {
      int col = wc * 64 + fj * 16 + lr;
      float bv = bias[n0 + col];
#pragma unroll
      for (int rr = 0; rr < 4; ++rr) {
        int row = wr * 64 + fi * 16 + lk * 4 + rr;
        SH[row * ES + col] = f2bf(acc[fi][fj][rr] + bv);
      }
    }
  __syncthreads();
  {
    int row = t >> 1, hcol = (t & 1) * 64;
    const unsigned short* sp = SH + row * ES + hcol;
    unsigned short* dp = Y + (size_t)(m0 + row) * Ndim + n0 + hcol;
#pragma unroll
    for (int j = 0; j < 8; ++j)
      *(bf16x8*)(dp + j * 8) = *(const bf16x8*)(sp + j * 8);
  }
}

// merged value + sampling-params GEMM: bx 0..1 -> value, 2..4 -> sa
__global__ __launch_bounds__(256)
void gemm_vs_k(const unsigned short* __restrict__ X0, const unsigned short* __restrict__ W0,
               const float* __restrict__ b0, unsigned short* __restrict__ Y0,
               const unsigned short* __restrict__ X1, const unsigned short* __restrict__ W1,
               const float* __restrict__ b1, unsigned short* __restrict__ Y1) {
  __shared__ unsigned short SH[SHN];
  int bx = blockIdx.x, m0 = blockIdx.y * 128;
  if (bx < 2)
    gemm_body(X0, W0, b0, Y0, 256, 256, bx * 128, m0, SH);
  else
    gemm_body(X1, W1, b1, Y1, 256, 384, (bx - 2) * 128, m0, SH);
}

// ---------------- 256-thread GEMM, tile 64x256, wave 64x64, fused ---------
// MODE 0: bias+ReLU -> Y (fc1).  MODE 1: x_mid = LN(res + C) -> Y (xm).
// MODE 2: x = LN(res + C) -> Y (xb), out1 (qb = x+pe).  MODE 3: +d_out f32.
// m0 = X-row base (chunk-local); mOut = rowOff + m0 = output-row base.
#define ESW 264
#define SHW 30720  // shorts: 3 bufs x 10240 (A 2048 + B 8192); epi 64*264=16896 fits

template <int MODE>
__global__ __launch_bounds__(256)
void gemmW_k(const unsigned short* __restrict__ X, const unsigned short* __restrict__ Wt,
             const float* __restrict__ bias, unsigned short* __restrict__ Y,
             const unsigned short* __restrict__ res, const float* __restrict__ g,
             const float* __restrict__ bta, const unsigned short* __restrict__ pe,
             unsigned short* __restrict__ out1, float* __restrict__ dout,
             int Kdim, int Ndim, int rowOff) {
  __shared__ unsigned short SH[SHW];
  const int t = threadIdx.x;
  const int n0 = (MODE == 0) ? blockIdx.x * 256 : 0;
  const int m0 = blockIdx.y * 64;      // X rows (chunk-local)
  const int mOut = rowOff + m0;        // output rows (global)
  const int wc = t >> 6;               // wave -> col quarter
  const int lane = t & 63;
  const int lr = lane & 15, lk = lane >> 4;
  // staging: A = 64x32 (256 slots), B = 256x32 (1024 slots); slot = row*4+sl
  const int rs = t >> 2, sl0 = t & 3;
  const unsigned short* xpA  = X + (size_t)(m0 + rs) * Kdim + swz(rs, sl0) * 8;
  const unsigned short* wpB0 = Wt + (size_t)(n0 + rs) * Kdim + swz(rs, sl0) * 8;
  const unsigned short* wpB1 = Wt + (size_t)(n0 + 64 + rs) * Kdim + swz(64 + rs, sl0) * 8;
  const unsigned short* wpB2 = Wt + (size_t)(n0 + 128 + rs) * Kdim + swz(128 + rs, sl0) * 8;
  const unsigned short* wpB3 = Wt + (size_t)(n0 + 192 + rs) * Kdim + swz(192 + rs, sl0) * 8;

  f32x4 acc[4][4];
#pragma unroll
  for (int i = 0; i < 4; ++i)
#pragma unroll
    for (int j = 0; j < 4; ++j)
#pragma unroll
      for (int e = 0; e < 4; ++e) acc[i][j][e] = 0.f;

  auto stage = [&](int buf, int kt) {
    unsigned short* base = SH + buf * 10240;
    gl16(xpA + kt, base + t * 8);
    gl16(wpB0 + kt, base + 2048 + t * 8);
    gl16(wpB1 + kt, base + 2048 + (256 + t) * 8);
    gl16(wpB2 + kt, base + 2048 + (512 + t) * 8);
    gl16(wpB3 + kt, base + 2048 + (768 + t) * 8);
  };

  const int nt = Kdim >> 5;
  stage(0, 0);
  stage(1, 32);
  asm volatile("s_waitcnt vmcnt(5)" ::: "memory");   // buf0's 5 done; buf1 in flight
  __builtin_amdgcn_s_barrier();

  int buf = 0;
  for (int ti = 0; ti < nt; ++ti) {
    if (ti + 2 < nt) stage(buf == 0 ? 2 : buf - 1, (ti + 2) << 5);
    const unsigned short* Ab = SH + buf * 10240;
    const unsigned short* Bb = Ab + 2048;
    bf16x8 ar[4], br[4];
#pragma unroll
    for (int fi = 0; fi < 4; ++fi) {
      int r = fi * 16 + lr;
      ar[fi] = *(const bf16x8*)&Ab[r * 32 + swz(r, lk) * 8];
    }
#pragma unroll
    for (int fj = 0; fj < 4; ++fj) {
      int r = wc * 64 + fj * 16 + lr;
      br[fj] = *(const bf16x8*)&Bb[r * 32 + swz(r, lk) * 8];
    }
#pragma unroll
    for (int fi = 0; fi < 4; ++fi)
#pragma unroll
      for (int fj = 0; fj < 4; ++fj)
        acc[fi][fj] = __builtin_amdgcn_mfma_f32_16x16x32_bf16(ar[fi], br[fj], acc[fi][fj], 0, 0, 0);
    if (ti + 2 < nt)
      asm volatile("s_waitcnt vmcnt(5)" ::: "memory");
    else
      asm volatile("s_waitcnt vmcnt(0)" ::: "memory");
    __builtin_amdgcn_s_barrier();
    buf = (buf == 2) ? 0 : buf + 1;
  }

  // stage C (+bias, +relu for MODE0) into LDS
#pragma unroll
  for (int fi = 0; fi < 4; ++fi)
#pragma unroll
    for (int fj = 0; fj < 4; ++fj) {
      int col = wc * 64 + fj * 16 + lr;
      float bv = bias[n0 + col];
#pragma unroll
      for (int rr = 0; rr < 4; ++rr) {
        int row = fi * 16 + lk * 4 + rr;
        float v = acc[fi][fj][rr] + bv;
        if constexpr (MODE == 0) v = fmaxf(v, 0.f);
        SH[row * ESW + col] = f2bf(v);
      }
    }
  __syncthreads();

  const int row = t >> 2;           // 64 rows, 4 threads/row
  const int c0 = (t & 3) * 64;      // 64 cols/thread
  const unsigned short* sp = SH + row * ESW + c0;

  if constexpr (MODE == 0) {
    unsigned short* dp = Y + (size_t)(m0 + row) * Ndim + n0 + c0;
#pragma unroll
    for (int j = 0; j < 8; ++j)
      *(bf16x8*)(dp + j * 8) = *(const bf16x8*)(sp + j * 8);
  } else {
    size_t rbase = (size_t)(mOut + row) * NC + c0;
    bf16x8 resv[8];
#pragma unroll
    for (int j = 0; j < 8; ++j) resv[j] = *(const bf16x8*)(res + rbase + j * 8);
    // pass 1: mean
    float sum = 0.f;
#pragma unroll
    for (int j = 0; j < 8; ++j) {
      f32x4 cl, ch, rl, rh;
      unp8(*(const bf16x8*)(sp + j * 8), cl, ch);
      unp8(resv[j], rl, rh);
      f32x4 a = cl + rl, b = ch + rh;
      sum += a[0] + a[1] + a[2] + a[3] + b[0] + b[1] + b[2] + b[3];
    }
    sum += __shfl_xor(sum, 1);
    sum += __shfl_xor(sum, 2);
    float mean = sum * (1.0f / NC);
    // pass 2: variance
    float s2 = 0.f;
#pragma unroll
    for (int j = 0; j < 8; ++j) {
      f32x4 cl, ch, rl, rh;
      unp8(*(const bf16x8*)(sp + j * 8), cl, ch);
      unp8(resv[j], rl, rh);
      f32x4 a = cl + rl - mean, b = ch + rh - mean;
      s2 += a[0]*a[0] + a[1]*a[1] + a[2]*a[2] + a[3]*a[3]
          + b[0]*b[0] + b[1]*b[1] + b[2]*b[2] + b[3]*b[3];
    }
    s2 += __shfl_xor(s2, 1);
    s2 += __shfl_xor(s2, 2);
    float rstd = rsqrtf(s2 * (1.0f / NC) + 1e-5f);
    // pass 3: normalize + write
#pragma unroll
    for (int j = 0; j < 8; ++j) {
      int col = c0 + j * 8;
      f32x4 cl, ch, rl, rh;
      unp8(*(const bf16x8*)(sp + j * 8), cl, ch);
      unp8(resv[j], rl, rh);
      f32x4 gl = *(const f32x4*)(g + col), gh = *(const f32x4*)(g + col + 4);
      f32x4 bl = *(const f32x4*)(bta + col), bh = *(const f32x4*)(bta + col + 4);
      f32x4 ol = (cl + rl - mean) * rstd * gl + bl;
      f32x4 oh = (ch + rh - mean) * rstd * gh + bh;
      *(bf16x8*)(Y + rbase + j * 8) = pck8(ol, oh);
      if constexpr (MODE >= 2) {
        f32x4 pl, ph;
        unp8(*(const bf16x8*)(pe + rbase + j * 8), pl, ph);
        *(bf16x8*)(out1 + rbase + j * 8) = pck8(ol + pl, oh + ph);
      }
      if constexpr (MODE == 3) {
        *(f32x4*)(dout + rbase + j * 8) = ol;
        *(f32x4*)(dout + rbase + j * 8 + 4) = oh;
      }
    }
  }
}

// ---------------- deformable sampling: one wave per (b,q) ----------------
// XCD-swizzled blockIdx: grid 10880 = 8 x 1360; each XCD gets one batch image
// (value slice 2.8MB fits per-XCD 4MB L2).
__global__ __launch_bounds__(256)
void samp_k(const unsigned short* __restrict__ value, const unsigned short* __restrict__ sa,
            unsigned short* __restrict__ attn_feat) {
  __shared__ float lw[4][128][4];
  __shared__ int   la[4][128][4];
  const int bid = blockIdx.x;
  const int sbid = (bid & 7) * 1360 + (bid >> 3);
  const int wid = threadIdx.x >> 6, lane = threadIdx.x & 63;
  const int bq = sbid * 4 + wid;
  const int q = bq % Q_;
  const int b = bq / Q_;

  int lvl = q < 4096 ? 0 : (q < 5120 ? 1 : (q < 5376 ? 2 : 3));
  int qrem = q - (lvl == 0 ? 0 : lvl == 1 ? 4096 : lvl == 2 ? 5120 : 5376);
  int wlog = 6 - lvl;
  float inv = __uint_as_float((unsigned)(127 - wlog) << 23);  // 1/2^wlog
  float refx = ((qrem & ((1 << wlog) - 1)) + 0.5f) * inv;
  float refy = ((qrem >> wlog) + 0.5f) * inv;
  const unsigned short* sa_bq = sa + (size_t)bq * 384;

  const int h_s = lane >> 3;
  const int s0 = (lane & 7) * 2;
  unsigned lg01 = *(const unsigned*)&sa_bq[256 + h_s * 16 + s0];
  float lg0 = bf2f((unsigned short)(lg01 & 0xffff));
  float lg1 = bf2f((unsigned short)(lg01 >> 16));
  float mx = fmaxf(lg0, lg1);
  mx = fmaxf(mx, __shfl_xor(mx, 1));
  mx = fmaxf(mx, __shfl_xor(mx, 2));
  mx = fmaxf(mx, __shfl_xor(mx, 4));
  float e0 = __expf(lg0 - mx), e1 = __expf(lg1 - mx);
  float sm = e0 + e1;
  sm += __shfl_xor(sm, 1);
  sm += __shfl_xor(sm, 2);
  sm += __shfl_xor(sm, 4);
  float rs = 1.0f / sm;

#pragma unroll
  for (int j = 0; j < 2; ++j) {
    int s = s0 + j;
    float aw = (j ? e1 : e0) * rs;
    unsigned oxy = *(const unsigned*)&sa_bq[h_s * 32 + s * 2];
    float ox = bf2f((unsigned short)(oxy & 0xffff));
    float oy = bf2f((unsigned short)(oxy >> 16));
    int sl = s >> 2;
    int swl = 6 - sl;
    int sw = 1 << swl;
    int sstart = (sl == 0) ? 0 : (sl == 1) ? 4096 : (sl == 2) ? 5120 : 5376;
    float x = fmaf(refx, (float)sw, ox) - 0.5f;
    float y = fmaf(refy, (float)sw, oy) - 0.5f;
    float x0f = floorf(x), y0f = floorf(y);
    float fx = x - x0f, fy = y - y0f;
    int x0 = (int)x0f, y0 = (int)y0f;
    int rowbase = b * Q_ + sstart;
    f32x4 wv; i32x4 av;
#pragma unroll
    for (int c = 0; c < 4; ++c) {
      int dy = c >> 1, dx = c & 1;
      int cy = y0 + dy, cx = x0 + dx;
      float wgt = (dy ? fy : 1.f - fy) * (dx ? fx : 1.f - fx);
      bool valid = (cy >= 0) & (cy < sw) & (cx >= 0) & (cx < sw);
      wgt = valid ? wgt : 0.f;
      int ccy = min(max(cy, 0), sw - 1);
      int ccx = min(max(cx, 0), sw - 1);
      wv[c] = wgt * aw;
      av[c] = ((rowbase + (ccy << swl) + ccx) * NH_ + h_s) * DH_;
    }
    int idx = s * 8 + (h_s ^ (s & 7));
    *(f32x4*)&lw[wid][idx][0] = wv;
    *(i32x4*)&la[wid][idx][0] = av;
  }
  __syncthreads();

  const int h = lane >> 3;
  const int half = (lane >> 2) & 1;
  const int quad = lane & 3;
  const unsigned short* vq = value + quad * 8;
  f32x4 accA = {0.f, 0.f, 0.f, 0.f}, accB = {0.f, 0.f, 0.f, 0.f};
#pragma unroll
  for (int i = 0; i < 8; ++i) {
    int s = half * 8 + i;
    int idx = s * 8 + (h ^ (s & 7));
    f32x4 wv = *(const f32x4*)&lw[wid][idx][0];
    i32x4 av = *(const i32x4*)&la[wid][idx][0];
#pragma unroll
    for (int c = 0; c < 4; ++c) {
      u32x4 gg = *(const u32x4*)(vq + av[c]);
      f32x4 v0, v1;
      v0[0] = __uint_as_float(gg[0] << 16); v0[1] = __uint_as_float(gg[0] & 0xffff0000u);
      v0[2] = __uint_as_float(gg[1] << 16); v0[3] = __uint_as_float(gg[1] & 0xffff0000u);
      v1[0] = __uint_as_float(gg[2] << 16); v1[1] = __uint_as_float(gg[2] & 0xffff0000u);
      v1[2] = __uint_as_float(gg[3] << 16); v1[3] = __uint_as_float(gg[3] & 0xffff0000u);
      float wcc = wv[c];
      accA += v0 * wcc;
      accB += v1 * wcc;
    }
  }
#pragma unroll
  for (int j = 0; j < 4; ++j) {
    accA[j] += __shfl_xor(accA[j], 4);
    accB[j] += __shfl_xor(accB[j], 4);
  }
  if (half == 0) {
    *(bf16x8*)(attn_feat + (size_t)bq * NC + h * DH_ + quad * 8) = pck8(accA, accB);
  }
}

// ---------------- launcher ----------------
extern "C" void kernel_launch(void* const* d_in, const int* in_sizes, int n_in,
                              void* d_out, int out_size, void* d_ws, size_t ws_size,
                              hipStream_t stream) {
  const float* src      = (const float*)d_in[0];
  const float* pos_flat = (const float*)d_in[1];
  const float* lvl_emb  = (const float*)d_in[2];
  const float* W_samp   = (const float*)d_in[3];
  const float* b_samp   = (const float*)d_in[4];
  const float* W_attn   = (const float*)d_in[5];
  const float* b_attn   = (const float*)d_in[6];
  const float* W_val    = (const float*)d_in[7];
  const float* b_val    = (const float*)d_in[8];
  const float* W_out    = (const float*)d_in[9];
  const float* b_out    = (const float*)d_in[10];
  const float* g1       = (const float*)d_in[11];
  const float* b1       = (const float*)d_in[12];
  const float* W_fc1    = (const float*)d_in[13];
  const float* b_fc1    = (const float*)d_in[14];
  const float* W_fc2    = (const float*)d_in[15];
  const float* b_fc2    = (const float*)d_in[16];
  const float* g2       = (const float*)d_in[17];
  const float* b2       = (const float*)d_in[18];

  char* ws = (char*)d_ws;
  size_t o = 0;
  auto alloc = [&](size_t bytes) {
    void* p = ws + o;
    o += (bytes + 255) & ~(size_t)255;
    return p;
  };
  unsigned short* bb    = (unsigned short*)alloc((size_t)MC2 * FFN_ * 2);  // value / hid chunk
  unsigned short* sa    = (unsigned short*)alloc((size_t)M_ * 384 * 2);    // offsets+logits
  unsigned short* af    = (unsigned short*)alloc((size_t)M_ * NC * 2);     // attn_feat
  unsigned short* xb    = (unsigned short*)alloc((size_t)M_ * NC * 2);     // bf16 residual x
  unsigned short* xm    = (unsigned short*)alloc((size_t)M_ * NC * 2);     // bf16 x_mid
  unsigned short* qb    = (unsigned short*)alloc((size_t)M_ * NC * 2);     // bf16(x+pe)
  unsigned short* pe    = (unsigned short*)alloc((size_t)M_ * NC * 2);     // bf16(pos+lvl)
  unsigned short* Wv_t  = (unsigned short*)alloc((size_t)6 * 256 * 256 * 2);
  unsigned short* Wsa_t = (unsigned short*)alloc((size_t)6 * 384 * 256 * 2);
  unsigned short* Wo_t  = (unsigned short*)alloc((size_t)6 * 256 * 256 * 2);
  unsigned short* Wf1_t = (unsigned short*)alloc((size_t)6 * 1024 * 256 * 2);
  unsigned short* Wf2_t = (unsigned short*)alloc((size_t)6 * 256 * 1024 * 2);
  float* bsa            = (float*)alloc((size_t)6 * 384 * 4);

  transpose_w2_k<<<1536, 256, 0, stream>>>(W_val, Wv_t, 6, 256, 256, 256, 0);
  transpose_w2_k<<<1536, 256, 0, stream>>>(W_samp, Wsa_t, 6, 256, 256, 384, 0);
  transpose_w2_k<<<768, 256, 0, stream>>>(W_attn, Wsa_t, 6, 256, 128, 384, 256);
  transpose_w2_k<<<1536, 256, 0, stream>>>(W_out, Wo_t, 6, 256, 256, 256, 0);
  transpose_w2_k<<<3072, 256, 0, stream>>>(W_fc1, Wf1_t, 6, 256, 1024, 1024, 0);
  transpose_w2_k<<<3072, 256, 0, stream>>>(W_fc2, Wf2_t, 6, 1024, 256, 256, 0);
  bias_cat_k<<<9, 256, 0, stream>>>(b_samp, b_attn, bsa);
  pre_k<<<M_ / 4, 256, 0, stream>>>(src, pos_flat, lvl_emb, xb, pe, qb);

  for (int i = 0; i < NLAYERS_; ++i) {
    // value = x @ Wv + bv  AND  sa = q @ [Ws|Wa] + [bs|ba]
    gemm_vs_k<<<dim3(5, M_ / 128), 256, 0, stream>>>(
        xb, Wv_t + (size_t)i * 65536, b_val + i * 256, bb,
        qb, Wsa_t + (size_t)i * 98304, bsa + i * 384, sa);
    // deformable sampling -> af (bf16)
    samp_k<<<M_ / 4, 256, 0, stream>>>(bb, sa, af);
    // x_mid = LN(x + af@Wo + bo) -> xm   (fused out-proj + ln_mid)
    gemmW_k<1><<<dim3(1, M_ / 64), 256, 0, stream>>>(
        af, Wo_t + (size_t)i * 65536, b_out + i * 256, xm,
        xb, g1 + i * 256, b1 + i * 256, nullptr, nullptr, nullptr, 256, 256, 0);
    // FFN in 2 chunks over M (hid shares bb)
    for (int c = 0; c < 2; ++c) {
      int rowOff = c * MC2;
      // hid = relu(xm @ Wfc1 + b)  (chunk-local in/out)
      gemmW_k<0><<<dim3(4, MC2 / 64), 256, 0, stream>>>(
          xm + (size_t)rowOff * NC, Wf1_t + (size_t)i * 262144, b_fc1 + i * 1024, bb,
          nullptr, nullptr, nullptr, nullptr, nullptr, nullptr, 256, 1024, 0);
      // x = LN(x_mid + hid@Wfc2 + b) -> xb, qb (+ d_out final)
      if (i == NLAYERS_ - 1)
        gemmW_k<3><<<dim3(1, MC2 / 64), 256, 0, stream>>>(
            bb, Wf2_t + (size_t)i * 262144, b_fc2 + i * 256, xb,
            xm, g2 + i * 256, b2 + i * 256, pe, qb, (float*)d_out, 1024, 256, rowOff);
      else
        gemmW_k<2><<<dim3(1, MC2 / 64), 256, 0, stream>>>(
            bb, Wf2_t + (size_t)i * 262144, b_fc2 + i * 256, xb,
            xm, g2 + i * 256, b2 + i * 256, pe, qb, nullptr, 1024, 256, rowOff);
    }
  }
}

// Round 13
// 1525.258 us; speedup vs baseline: 1.1706x; 1.1706x over previous
//
#include <hip/hip_runtime.h>
#include <hip/hip_bf16.h>

#define NB 8
#define NC 256
#define NH_ 8
#define NLAYERS_ 6
#define FFN_ 1024
#define Q_ 5440
#define DH_ 32
#define M_ (NB*Q_)        // 43520
#define MC2 (M_/2)        // 21760  (FFN chunk rows, fallback)

typedef __attribute__((ext_vector_type(8))) short bf16x8;
typedef __attribute__((ext_vector_type(4))) short bf16x4;
typedef __attribute__((ext_vector_type(4))) float f32x4;
typedef __attribute__((ext_vector_type(4))) int i32x4;
typedef __attribute__((ext_vector_type(4))) unsigned int u32x4;
typedef unsigned int u32;

__device__ __forceinline__ unsigned short f2bf(float f) {
  unsigned int u = __float_as_uint(f);
  u += 0x7fffu + ((u >> 16) & 1u);
  return (unsigned short)(u >> 16);
}
__device__ __forceinline__ float bf2f(unsigned short s) {
  return __uint_as_float(((unsigned int)s) << 16);
}
__device__ __forceinline__ void gl16(const unsigned short* g, unsigned short* l) {
  __builtin_amdgcn_global_load_lds((const __attribute__((address_space(1))) u32*)(g),
                                   (__attribute__((address_space(3))) u32*)(l), 16, 0, 0);
}

// ---------------- prep kernels ----------------
__global__ void transpose_w2_k(const float* __restrict__ W, unsigned short* __restrict__ Wt,
                               int L, int Kd, int Nd, int NdTot, int nOff) {
  size_t total = (size_t)L * Nd * Kd;
  for (size_t i = (size_t)blockIdx.x * blockDim.x + threadIdx.x; i < total;
       i += (size_t)gridDim.x * blockDim.x) {
    int k = (int)(i % Kd);
    size_t r = i / Kd;
    int n = (int)(r % Nd);
    int l = (int)(r / Nd);
    Wt[((size_t)l * NdTot + nOff + n) * Kd + k] = f2bf(W[((size_t)l * Kd + k) * Nd + n]);
  }
}

__global__ void bias_cat_k(const float* __restrict__ bs, const float* __restrict__ ba,
                           float* __restrict__ bsa) {
  int i = blockIdx.x * blockDim.x + threadIdx.x;
  if (i >= NLAYERS_ * 384) return;
  int l = i / 384, n = i % 384;
  bsa[i] = (n < 256) ? bs[l * 256 + n] : ba[l * 128 + (n - 256)];
}

// layer-0: xb=bf16(src), pe=bf16(pos+lvl), qb=bf16(src+pos+lvl)
__global__ __launch_bounds__(256)
void pre_k(const float* __restrict__ src, const float* __restrict__ pf,
           const float* __restrict__ le, unsigned short* __restrict__ xb,
           unsigned short* __restrict__ pe, unsigned short* __restrict__ qb) {
  int row = blockIdx.x * 4 + (threadIdx.x >> 6);
  int lane = threadIdx.x & 63;
  size_t base = (size_t)row * NC + lane * 4;
  int q = row % Q_;
  int lvl = q < 4096 ? 0 : (q < 5120 ? 1 : (q < 5376 ? 2 : 3));
  f32x4 xv = *(const f32x4*)(src + base);
  f32x4 pv = *(const f32x4*)(pf + base) + *(const f32x4*)(le + lvl * NC + lane * 4);
  f32x4 qv = xv + pv;
  bf16x4 xo, po, qo;
#pragma unroll
  for (int j = 0; j < 4; ++j) {
    xo[j] = (short)f2bf(xv[j]); po[j] = (short)f2bf(pv[j]); qo[j] = (short)f2bf(qv[j]);
  }
  *(bf16x4*)(xb + base) = xo;
  *(bf16x4*)(pe + base) = po;
  *(bf16x4*)(qb + base) = qo;
}

// ---------------- GEMM body: Y[.,N] = X[.,K] @ Wt[N,K]^T + bias ------------
// 128x128 tile, BK=32, 4 waves (2x2), wave 64x64 = 4x4 frags of 16x16x32.
// 3-buffer pipeline, counted vmcnt(4) + raw s_barrier. Epilogue via LDS.
__device__ __forceinline__ int swz(int r, int sl) { return sl ^ (r & 3) ^ ((r >> 2) & 3); }
#define ES 136            // epilogue LDS row stride (shorts)
#define SHN 24576         // shorts: 3 bufs x (A 4096 + B 4096) = 48KB; epi 34.8KB fits

template <bool RELU>
__device__ __forceinline__ void gemm_body(const unsigned short* X, const unsigned short* Wt,
                                          const float* bias, unsigned short* Y,
                                          int Kdim, int Ndim, int n0, int m0,
                                          unsigned short* SH) {
  const int t = threadIdx.x;
  const int wave = t >> 6, lane = t & 63;
  const int wr = wave >> 1, wc = wave & 1;
  const int lr = lane & 15, lk = lane >> 4;
  const int r0 = t >> 2, sl0 = t & 3;
  const int r1 = (256 + t) >> 2;
  const int gs0 = swz(r0, sl0);
  const int gs1 = swz(r1, sl0);
  const unsigned short* xp0 = X + (size_t)(m0 + r0) * Kdim + gs0 * 8;
  const unsigned short* wp0 = Wt + (size_t)(n0 + r0) * Kdim + gs0 * 8;
  const unsigned short* xp1 = X + (size_t)(m0 + r1) * Kdim + gs1 * 8;
  const unsigned short* wp1 = Wt + (size_t)(n0 + r1) * Kdim + gs1 * 8;

  f32x4 acc[4][4];
#pragma unroll
  for (int i = 0; i < 4; ++i)
#pragma unroll
    for (int j = 0; j < 4; ++j)
#pragma unroll
      for (int e = 0; e < 4; ++e) acc[i][j][e] = 0.f;

  auto stage = [&](int buf, int kt) {
    unsigned short* base = SH + buf * 8192;
    gl16(xp0 + kt, base + t * 8);
    gl16(wp0 + kt, base + 4096 + t * 8);
    gl16(xp1 + kt, base + (256 + t) * 8);
    gl16(wp1 + kt, base + 4096 + (256 + t) * 8);
  };

  const int nt = Kdim >> 5;
  stage(0, 0);
  stage(1, 32);
  asm volatile("s_waitcnt vmcnt(4)" ::: "memory");   // buf0 ready; buf1 in flight
  __builtin_amdgcn_s_barrier();

  int buf = 0;
  for (int ti = 0; ti < nt; ++ti) {
    if (ti + 2 < nt) stage(buf == 0 ? 2 : buf - 1, (ti + 2) << 5);  // (ti+2)%3
    const unsigned short* Ab = SH + buf * 8192;
    const unsigned short* Bb = Ab + 4096;
    bf16x8 ar[4], br[4];
#pragma unroll
    for (int fi = 0; fi < 4; ++fi) {
      int r = wr * 64 + fi * 16 + lr;
      ar[fi] = *(const bf16x8*)&Ab[r * 32 + swz(r, lk) * 8];
    }
#pragma unroll
    for (int fj = 0; fj < 4; ++fj) {
      int r = wc * 64 + fj * 16 + lr;
      br[fj] = *(const bf16x8*)&Bb[r * 32 + swz(r, lk) * 8];
    }
#pragma unroll
    for (int fi = 0; fi < 4; ++fi)
#pragma unroll
      for (int fj = 0; fj < 4; ++fj)
        acc[fi][fj] = __builtin_amdgcn_mfma_f32_16x16x32_bf16(ar[fi], br[fj], acc[fi][fj], 0, 0, 0);
    if (ti + 2 < nt)
      asm volatile("s_waitcnt vmcnt(4)" ::: "memory");
    else
      asm volatile("s_waitcnt vmcnt(0)" ::: "memory");
    __builtin_amdgcn_s_barrier();
    buf = (buf == 2) ? 0 : buf + 1;
  }

  // epilogue: C/D layout col=lane&15, row=(lane>>4)*4+reg  [HW-verified]
#pragma unroll
  for (int fi = 0; fi < 4; ++fi)
#pragma unroll
    for (int fj = 0; fj < 4; ++fj) {
      int col = wc * 64 + fj * 16 + lr;
      float bv = bias[n0 + col];
#pragma unroll
      for (int rr = 0; rr < 4; ++rr) {
        int row = wr * 64 + fi * 16 + lk * 4 + rr;
        float v = acc[fi][fj][rr] + bv;
        if constexpr (RELU) v = fmaxf(v, 0.f);
        SH[row * ES + col] = f2bf(v);
      }
    }
  __syncthreads();
  {
    int row = t >> 1, hcol = (t & 1) * 64;
    const unsigned short* sp = SH + row * ES + hcol;
    unsigned short* dp = Y + (size_t)(m0 + row) * Ndim + n0 + hcol;
#pragma unroll
    for (int j = 0; j < 8; ++j)
      *(bf16x8*)(dp + j * 8) = *(const bf16x8*)(sp + j * 8);
  }
}

template <bool RELU>
__global__ __launch_bounds__(256)
void gemm_k(const unsigned short* __restrict__ X, const unsigned short* __restrict__ Wt,
            const float* __restrict__ bias, unsigned short* __restrict__ Y,
            int Kdim, int Ndim) {
  __shared__ unsigned short SH[SHN];
  gemm_body<RELU>(X, Wt, bias, Y, Kdim, Ndim, blockIdx.x * 128, blockIdx.y * 128, SH);
}

// merged value + sampling-params GEMM: bx 0..1 -> value, 2..4 -> sa
__global__ __launch_bounds__(256)
void gemm_vs_k(const unsigned short* __restrict__ X0, const unsigned short* __restrict__ W0,
               const float* __restrict__ b0, unsigned short* __restrict__ Y0,
               const unsigned short* __restrict__ X1, const unsigned short* __restrict__ W1,
               const float* __restrict__ b1, unsigned short* __restrict__ Y1) {
  __shared__ unsigned short SH[SHN];
  int bx = blockIdx.x, m0 = blockIdx.y * 128;
  if (bx < 2)
    gemm_body<false>(X0, W0, b0, Y0, 256, 256, bx * 128, m0, SH);
  else
    gemm_body<false>(X1, W1, b1, Y1, 256, 384, (bx - 2) * 128, m0, SH);
}

// ---------------- deformable sampling: one wave per (b,q) ----------------
// XCD-swizzled blockIdx: grid 10880 = 8 x 1360; each XCD gets one batch image
// (value slice 2.8MB fits per-XCD 4MB L2) [proven: FETCH 52.7->36.7 MB].
__global__ __launch_bounds__(256)
void samp_k(const unsigned short* __restrict__ value, const unsigned short* __restrict__ sa,
            unsigned short* __restrict__ attn_feat) {
  __shared__ float lw[4][128][4];
  __shared__ int   la[4][128][4];
  const int bid = blockIdx.x;
  const int sbid = (bid & 7) * 1360 + (bid >> 3);
  const int wid = threadIdx.x >> 6, lane = threadIdx.x & 63;
  const int bq = sbid * 4 + wid;
  const int q = bq % Q_;
  const int b = bq / Q_;

  int lvl = q < 4096 ? 0 : (q < 5120 ? 1 : (q < 5376 ? 2 : 3));
  int qrem = q - (lvl == 0 ? 0 : lvl == 1 ? 4096 : lvl == 2 ? 5120 : 5376);
  int wlog = 6 - lvl;
  float inv = __uint_as_float((unsigned)(127 - wlog) << 23);  // 1/2^wlog
  float refx = ((qrem & ((1 << wlog) - 1)) + 0.5f) * inv;
  float refy = ((qrem >> wlog) + 0.5f) * inv;
  const unsigned short* sa_bq = sa + (size_t)bq * 384;

  // ---- setup: h_s = lane>>3, samples s0, s0+1 ----
  const int h_s = lane >> 3;
  const int s0 = (lane & 7) * 2;
  unsigned lg01 = *(const unsigned*)&sa_bq[256 + h_s * 16 + s0];
  float lg0 = bf2f((unsigned short)(lg01 & 0xffff));
  float lg1 = bf2f((unsigned short)(lg01 >> 16));
  float mx = fmaxf(lg0, lg1);
  mx = fmaxf(mx, __shfl_xor(mx, 1));
  mx = fmaxf(mx, __shfl_xor(mx, 2));
  mx = fmaxf(mx, __shfl_xor(mx, 4));
  float e0 = __expf(lg0 - mx), e1 = __expf(lg1 - mx);
  float sm = e0 + e1;
  sm += __shfl_xor(sm, 1);
  sm += __shfl_xor(sm, 2);
  sm += __shfl_xor(sm, 4);
  float rs = 1.0f / sm;

#pragma unroll
  for (int j = 0; j < 2; ++j) {
    int s = s0 + j;
    float aw = (j ? e1 : e0) * rs;
    unsigned oxy = *(const unsigned*)&sa_bq[h_s * 32 + s * 2];
    float ox = bf2f((unsigned short)(oxy & 0xffff));
    float oy = bf2f((unsigned short)(oxy >> 16));
    int sl = s >> 2;
    int swl = 6 - sl;
    int sw = 1 << swl;
    int sstart = (sl == 0) ? 0 : (sl == 1) ? 4096 : (sl == 2) ? 5120 : 5376;
    float x = fmaf(refx, (float)sw, ox) - 0.5f;
    float y = fmaf(refy, (float)sw, oy) - 0.5f;
    float x0f = floorf(x), y0f = floorf(y);
    float fx = x - x0f, fy = y - y0f;
    int x0 = (int)x0f, y0 = (int)y0f;
    int rowbase = b * Q_ + sstart;
    f32x4 wv; i32x4 av;
#pragma unroll
    for (int c = 0; c < 4; ++c) {
      int dy = c >> 1, dx = c & 1;
      int cy = y0 + dy, cx = x0 + dx;
      float wgt = (dy ? fy : 1.f - fy) * (dx ? fx : 1.f - fx);
      bool valid = (cy >= 0) & (cy < sw) & (cx >= 0) & (cx < sw);
      wgt = valid ? wgt : 0.f;
      int ccy = min(max(cy, 0), sw - 1);
      int ccx = min(max(cx, 0), sw - 1);
      wv[c] = wgt * aw;
      av[c] = ((rowbase + (ccy << swl) + ccx) * NH_ + h_s) * DH_;
    }
    int idx = s * 8 + (h_s ^ (s & 7));
    *(f32x4*)&lw[wid][idx][0] = wv;
    *(i32x4*)&la[wid][idx][0] = av;
  }
  __syncthreads();

  // ---- gather (bf16 value, u32 unpack, f32x4 vector accumulate) ----
  const int h = lane >> 3;
  const int half = (lane >> 2) & 1;
  const int quad = lane & 3;
  const unsigned short* vq = value + quad * 8;
  f32x4 accA = {0.f, 0.f, 0.f, 0.f}, accB = {0.f, 0.f, 0.f, 0.f};
#pragma unroll
  for (int i = 0; i < 8; ++i) {
    int s = half * 8 + i;
    int idx = s * 8 + (h ^ (s & 7));
    f32x4 wv = *(const f32x4*)&lw[wid][idx][0];
    i32x4 av = *(const i32x4*)&la[wid][idx][0];
#pragma unroll
    for (int c = 0; c < 4; ++c) {
      u32x4 gg = *(const u32x4*)(vq + av[c]);
      f32x4 v0, v1;
      v0[0] = __uint_as_float(gg[0] << 16); v0[1] = __uint_as_float(gg[0] & 0xffff0000u);
      v0[2] = __uint_as_float(gg[1] << 16); v0[3] = __uint_as_float(gg[1] & 0xffff0000u);
      v1[0] = __uint_as_float(gg[2] << 16); v1[1] = __uint_as_float(gg[2] & 0xffff0000u);
      v1[2] = __uint_as_float(gg[3] << 16); v1[3] = __uint_as_float(gg[3] & 0xffff0000u);
      float wcc = wv[c];
      accA += v0 * wcc;
      accB += v1 * wcc;
    }
  }
#pragma unroll
  for (int j = 0; j < 4; ++j) {
    accA[j] += __shfl_xor(accA[j], 4);
    accB[j] += __shfl_xor(accB[j], 4);
  }
  if (half == 0) {
    bf16x8 ov;
    ov[0] = (short)f2bf(accA[0]); ov[1] = (short)f2bf(accA[1]);
    ov[2] = (short)f2bf(accA[2]); ov[3] = (short)f2bf(accA[3]);
    ov[4] = (short)f2bf(accB[0]); ov[5] = (short)f2bf(accB[1]);
    ov[6] = (short)f2bf(accB[2]); ov[7] = (short)f2bf(accB[3]);
    *(bf16x8*)(attn_feat + (size_t)bq * NC + h * DH_ + quad * 8) = ov;
  }
}

// ---------------- LayerNorm variants (all-bf16 residual stream) ------------
__device__ __forceinline__ f32x4 ln_core(f32x4 xv, const float* g, const float* bta, int lane) {
  float ssum = xv[0] + xv[1] + xv[2] + xv[3];
#pragma unroll
  for (int o = 1; o <= 32; o <<= 1) ssum += __shfl_xor(ssum, o);
  float mean = ssum * (1.0f / NC);
  f32x4 cv = xv - mean;
  float s2 = cv[0] * cv[0] + cv[1] * cv[1] + cv[2] * cv[2] + cv[3] * cv[3];
#pragma unroll
  for (int o = 1; o <= 32; o <<= 1) s2 += __shfl_xor(s2, o);
  float rstd = rsqrtf(s2 * (1.0f / NC) + 1e-5f);
  f32x4 gv = *(const f32x4*)(g + lane * 4);
  f32x4 bv = *(const f32x4*)(bta + lane * 4);
  return cv * rstd * gv + bv;
}
__device__ __forceinline__ f32x4 ldbf4(const unsigned short* p) {
  bf16x4 v = *(const bf16x4*)p;
  f32x4 r;
#pragma unroll
  for (int j = 0; j < 4; ++j) r[j] = bf2f((unsigned short)v[j]);
  return r;
}
__device__ __forceinline__ void stbf4(unsigned short* p, f32x4 v) {
  bf16x4 o;
#pragma unroll
  for (int j = 0; j < 4; ++j) o[j] = (short)f2bf(v[j]);
  *(bf16x4*)p = o;
}

// x_mid = LN(x + y)  (bf16 in, bf16 out)
__global__ __launch_bounds__(256)
void ln_mid_k(const unsigned short* __restrict__ xb, const unsigned short* __restrict__ delta,
              const float* __restrict__ g, const float* __restrict__ bta,
              unsigned short* __restrict__ xm) {
  int row = blockIdx.x * 4 + (threadIdx.x >> 6);
  int lane = threadIdx.x & 63;
  size_t base = (size_t)row * NC + lane * 4;
  f32x4 xv = ldbf4(xb + base) + ldbf4(delta + base);
  f32x4 ov = ln_core(xv, g, bta, lane);
  stbf4(xm + base, ov);
}

// x = LN(x_mid + y2): writes xb (bf16), qb = bf16(x+pe); FINAL also d_out f32
template <bool FINAL>
__global__ __launch_bounds__(256)
void ln_end_k(const unsigned short* __restrict__ xm, const unsigned short* __restrict__ delta,
              const float* __restrict__ g, const float* __restrict__ bta,
              const unsigned short* __restrict__ pe,
              unsigned short* __restrict__ xb, unsigned short* __restrict__ qb,
              float* __restrict__ outf) {
  int row = blockIdx.x * 4 + (threadIdx.x >> 6);
  int lane = threadIdx.x & 63;
  size_t base = (size_t)row * NC + lane * 4;
  f32x4 xv = ldbf4(xm + base) + ldbf4(delta + base);
  f32x4 ov = ln_core(xv, g, bta, lane);
  stbf4(xb + base, ov);
  f32x4 qv = ov + ldbf4(pe + base);
  stbf4(qb + base, qv);
  if constexpr (FINAL) *(f32x4*)(outf + base) = ov;
}

// ---------------- launcher ----------------
extern "C" void kernel_launch(void* const* d_in, const int* in_sizes, int n_in,
                              void* d_out, int out_size, void* d_ws, size_t ws_size,
                              hipStream_t stream) {
  const float* src      = (const float*)d_in[0];
  const float* pos_flat = (const float*)d_in[1];
  const float* lvl_emb  = (const float*)d_in[2];
  const float* W_samp   = (const float*)d_in[3];
  const float* b_samp   = (const float*)d_in[4];
  const float* W_attn   = (const float*)d_in[5];
  const float* b_attn   = (const float*)d_in[6];
  const float* W_val    = (const float*)d_in[7];
  const float* b_val    = (const float*)d_in[8];
  const float* W_out    = (const float*)d_in[9];
  const float* b_out    = (const float*)d_in[10];
  const float* g1       = (const float*)d_in[11];
  const float* b1       = (const float*)d_in[12];
  const float* W_fc1    = (const float*)d_in[13];
  const float* b_fc1    = (const float*)d_in[14];
  const float* W_fc2    = (const float*)d_in[15];
  const float* b_fc2    = (const float*)d_in[16];
  const float* g2       = (const float*)d_in[17];
  const float* b2       = (const float*)d_in[18];

  // FFN chunking: unchunked needs hid = M*1024 bf16 (89MB, total ~243MB);
  // fall back to 2 chunks (hid 44.6MB, total ~199MB — proven safe) if ws small.
  const bool big = ws_size >= (size_t)246 * 1024 * 1024;
  const int nchunks = big ? 1 : 2;
  const int chrows = big ? M_ : MC2;

  char* ws = (char*)d_ws;
  size_t o = 0;
  auto alloc = [&](size_t bytes) {
    void* p = ws + o;
    o += (bytes + 255) & ~(size_t)255;
    return p;
  };
  unsigned short* bb    = (unsigned short*)alloc((size_t)chrows * FFN_ * 2); // value / hid
  unsigned short* sa    = (unsigned short*)alloc((size_t)M_ * 384 * 2);      // offsets+logits / y / y2
  unsigned short* af    = (unsigned short*)alloc((size_t)M_ * NC * 2);       // attn_feat
  unsigned short* xb    = (unsigned short*)alloc((size_t)M_ * NC * 2);       // bf16 residual x
  unsigned short* xm    = (unsigned short*)alloc((size_t)M_ * NC * 2);       // bf16 x_mid
  unsigned short* qb    = (unsigned short*)alloc((size_t)M_ * NC * 2);       // bf16(x+pe)
  unsigned short* pe    = (unsigned short*)alloc((size_t)M_ * NC * 2);       // bf16(pos+lvl)
  unsigned short* Wv_t  = (unsigned short*)alloc((size_t)6 * 256 * 256 * 2);
  unsigned short* Wsa_t = (unsigned short*)alloc((size_t)6 * 384 * 256 * 2);
  unsigned short* Wo_t  = (unsigned short*)alloc((size_t)6 * 256 * 256 * 2);
  unsigned short* Wf1_t = (unsigned short*)alloc((size_t)6 * 1024 * 256 * 2);
  unsigned short* Wf2_t = (unsigned short*)alloc((size_t)6 * 256 * 1024 * 2);
  float* bsa            = (float*)alloc((size_t)6 * 384 * 4);

  transpose_w2_k<<<1536, 256, 0, stream>>>(W_val, Wv_t, 6, 256, 256, 256, 0);
  transpose_w2_k<<<1536, 256, 0, stream>>>(W_samp, Wsa_t, 6, 256, 256, 384, 0);
  transpose_w2_k<<<768, 256, 0, stream>>>(W_attn, Wsa_t, 6, 256, 128, 384, 256);
  transpose_w2_k<<<1536, 256, 0, stream>>>(W_out, Wo_t, 6, 256, 256, 256, 0);
  transpose_w2_k<<<3072, 256, 0, stream>>>(W_fc1, Wf1_t, 6, 256, 1024, 1024, 0);
  transpose_w2_k<<<3072, 256, 0, stream>>>(W_fc2, Wf2_t, 6, 1024, 256, 256, 0);
  bias_cat_k<<<9, 256, 0, stream>>>(b_samp, b_attn, bsa);
  pre_k<<<M_ / 4, 256, 0, stream>>>(src, pos_flat, lvl_emb, xb, pe, qb);

  for (int i = 0; i < NLAYERS_; ++i) {
    // value = x @ Wv + bv  AND  sa = q @ [Ws|Wa] + [bs|ba]
    gemm_vs_k<<<dim3(5, M_ / 128), 256, 0, stream>>>(
        xb, Wv_t + (size_t)i * 65536, b_val + i * 256, bb,
        qb, Wsa_t + (size_t)i * 98304, bsa + i * 384, sa);
    // deformable sampling -> af (bf16)
    samp_k<<<M_ / 4, 256, 0, stream>>>(bb, sa, af);
    // y = af @ Wo + bo (into sa, stride 256)
    gemm_k<false><<<dim3(2, M_ / 128), 256, 0, stream>>>(
        af, Wo_t + (size_t)i * 65536, b_out + i * 256, sa, 256, 256);
    // x_mid = LN(x + y) -> xm (bf16; also fc1 input)
    ln_mid_k<<<M_ / 4, 256, 0, stream>>>(xb, sa, g1 + i * 256, b1 + i * 256, xm);
    // FFN over M in nchunks (hid shares bb)
    for (int c = 0; c < nchunks; ++c) {
      gemm_k<true><<<dim3(8, chrows / 128), 256, 0, stream>>>(
          xm + (size_t)c * chrows * NC, Wf1_t + (size_t)i * 262144, b_fc1 + i * 1024,
          bb, 256, 1024);
      gemm_k<false><<<dim3(2, chrows / 128), 256, 0, stream>>>(
          bb, Wf2_t + (size_t)i * 262144, b_fc2 + i * 256,
          sa + (size_t)c * chrows * NC, 1024, 256);
    }
    // x = LN(x_mid + y2) -> xb, qb (+ d_out on final layer)
    if (i == NLAYERS_ - 1)
      ln_end_k<true><<<M_ / 4, 256, 0, stream>>>(xm, sa, g2 + i * 256, b2 + i * 256,
                                                 pe, xb, qb, (float*)d_out);
    else
      ln_end_k<false><<<M_ / 4, 256, 0, stream>>>(xm, sa, g2 + i * 256, b2 + i * 256,
                                                  pe, xb, qb, nullptr);
  }
}